// Round 1
// baseline (65.871 us; speedup 1.0000x reference)
//
#include <hip/hip_runtime.h>
#include <math.h>

#define HH 512
#define WW 512
#define CC 6

static constexpr float BIGD = (float)(HH + WW);   // cap, matches reference BIG = h+w
static constexpr float INV2SIG2 = 1.0f / (2.0f * 10.0f * 10.0f);

// ---------------- kernel 1: non-background mask ----------------
__global__ void k_nb(const float* __restrict__ target, float* __restrict__ nb) {
    int p = blockIdx.x * blockDim.x + threadIdx.x;
    if (p >= HH * WW) return;
    const float* t = target + (size_t)p * CC;
    bool any = (t[0] > 0.0f) | (t[1] > 0.0f) | (t[2] > 0.0f) | (t[3] > 0.0f) | (t[4] > 0.0f);
    nb[p] = any ? 1.0f : 0.0f;
}

// ---------------- kernel 2: vertical capped distance pass ----------------
// One thread per column. fwd pass stores distance into g; bwd pass combines
// and squares: g = min(fwd, bwd)^2.  Exactly mirrors the reference scans.
__global__ void k_vert(const float* __restrict__ nb, float* __restrict__ g) {
    int x = blockIdx.x * blockDim.x + threadIdx.x;
    if (x >= WW) return;
    float d = BIGD;
    for (int i = 0; i < HH; ++i) {
        float r = nb[i * WW + x];
        d = (r > 0.0f) ? 0.0f : fminf(d + 1.0f, BIGD);
        g[i * WW + x] = d;
    }
    d = BIGD;
    for (int i = HH - 1; i >= 0; --i) {
        float r = nb[i * WW + x];
        d = (r > 0.0f) ? 0.0f : fminf(d + 1.0f, BIGD);
        float f = fminf(g[i * WW + x], d);
        g[i * WW + x] = f * f;
    }
}

// ---------------- kernel 3: horizontal EDT + CE + weight + row reduce ----------------
__global__ __launch_bounds__(512) void k_row(const float* __restrict__ pred,
                                             const float* __restrict__ target,
                                             const float* __restrict__ g,
                                             float* __restrict__ partials) {
    __shared__ float gs[WW];
    __shared__ float red[8];
    const int i = blockIdx.x;
    const int x = threadIdx.x;

    gs[x] = g[i * WW + x];
    __syncthreads();

    // outward search: equivalent to min_k gs[k] + (x-k)^2 because gs >= 0,
    // so any radius r with r*r >= best cannot improve.
    float best = gs[x];
    for (int r = 1; r < WW; ++r) {
        float rr = (float)(r * r);
        if (rr >= best) break;
        int kl = x - r;
        int kr = x + r;
        if (kl >= 0) best = fminf(best, gs[kl] + rr);
        if (kr < WW) best = fminf(best, gs[kr] + rr);
    }
    float bg_w = expf(-best * INV2SIG2);

    // soft-target CE with log-softmax over C=6
    const int p = i * WW + x;
    float pv[CC];
#pragma unroll
    for (int c = 0; c < CC; ++c) pv[c] = pred[c * (HH * WW) + p];
    float m = pv[0];
#pragma unroll
    for (int c = 1; c < CC; ++c) m = fmaxf(m, pv[c]);
    float s = 0.0f;
#pragma unroll
    for (int c = 0; c < CC; ++c) s += expf(pv[c] - m);
    float lse = m + logf(s);
    const float* t = target + (size_t)p * CC;
    float ce = 0.0f;
#pragma unroll
    for (int c = 0; c < CC; ++c) ce += t[c] * (lse - pv[c]);

    float contrib = ce * (5.0f + bg_w);

    // block reduction: wave64 shuffle then cross-wave via LDS
#pragma unroll
    for (int off = 32; off > 0; off >>= 1) contrib += __shfl_down(contrib, off, 64);
    if ((x & 63) == 0) red[x >> 6] = contrib;
    __syncthreads();
    if (x == 0) {
        float sum = 0.0f;
#pragma unroll
        for (int w = 0; w < 8; ++w) sum += red[w];
        partials[i] = sum;
    }
}

// ---------------- kernel 4: final reduce ----------------
__global__ void k_final(const float* __restrict__ partials, float* __restrict__ out) {
    __shared__ float red[8];
    const int x = threadIdx.x;  // 512 threads
    float v = partials[x];
#pragma unroll
    for (int off = 32; off > 0; off >>= 1) v += __shfl_down(v, off, 64);
    if ((x & 63) == 0) red[x >> 6] = v;
    __syncthreads();
    if (x == 0) {
        float sum = 0.0f;
#pragma unroll
        for (int w = 0; w < 8; ++w) sum += red[w];
        out[0] = sum / (float)(CC * HH * WW);
    }
}

extern "C" void kernel_launch(void* const* d_in, const int* in_sizes, int n_in,
                              void* d_out, int out_size, void* d_ws, size_t ws_size,
                              hipStream_t stream) {
    const float* pred   = (const float*)d_in[0];   // [1,6,512,512]
    const float* target = (const float*)d_in[1];   // [1,512,512,6]
    float* ws = (float*)d_ws;
    float* g        = ws;                 // H*W floats
    float* nb       = ws + HH * WW;       // H*W floats
    float* partials = ws + 2 * HH * WW;   // H floats
    float* out = (float*)d_out;

    k_nb  <<<(HH * WW + 255) / 256, 256, 0, stream>>>(target, nb);
    k_vert<<<2, 256, 0, stream>>>(nb, g);
    k_row <<<HH, WW, 0, stream>>>(pred, target, g, partials);
    k_final<<<1, 512, 0, stream>>>(partials, out);
}

// Round 2
// 11.406 us; speedup vs baseline: 5.7752x; 5.7752x over previous
//
#include <hip/hip_runtime.h>
#include <math.h>

#define HH 512
#define WW 512
#define CC 6

static constexpr float BIGD = (float)(HH + WW);   // cap, matches reference BIG = h+w
static constexpr float INV2SIG2 = 1.0f / (2.0f * 10.0f * 10.0f);

__device__ __forceinline__ bool is_nb(const float* __restrict__ target, int p) {
    const float* t = target + (size_t)p * CC;
    return (t[0] > 0.0f) | (t[1] > 0.0f) | (t[2] > 0.0f) | (t[3] > 0.0f) | (t[4] > 0.0f);
}

// ---------------- fused kernel: vertical EDT (ring search) + horizontal EDT
// + log-softmax CE + weighting + row reduce ----------------
__global__ __launch_bounds__(512) void k_main(const float* __restrict__ pred,
                                              const float* __restrict__ target,
                                              float* __restrict__ partials) {
    __shared__ float gs[WW];
    __shared__ float red[8];
    const int i = blockIdx.x;
    const int x = threadIdx.x;
    const int p = i * WW + x;

    // --- vertical distance: nearest non-background pixel in this column ---
    // Equivalent to min(fwd,bwd) of the reference's capped scans: the cap
    // (BIG=1024) only binds when the whole column is background, in which
    // case we also return BIGD.
    float dist;
    if (is_nb(target, p)) {
        dist = 0.0f;
    } else {
        dist = BIGD;
        for (int k = 1; k < HH; ++k) {
            const int iu = i - k, id = i + k;
            bool out_of_range = true;
            if (iu >= 0) {
                out_of_range = false;
                if (is_nb(target, iu * WW + x)) { dist = (float)k; break; }
            }
            if (id < HH) {
                out_of_range = false;
                if (is_nb(target, id * WW + x)) { dist = (float)k; break; }
            }
            if (out_of_range) break;
        }
    }
    gs[x] = dist * dist;
    __syncthreads();

    // --- horizontal EDT: outward search; exact because gs >= 0, so any
    // radius r with r*r >= best cannot improve min_k gs[k] + (x-k)^2 ---
    float best = gs[x];
    for (int r = 1; r < WW; ++r) {
        float rr = (float)(r * r);
        if (rr >= best) break;
        int kl = x - r;
        int kr = x + r;
        if (kl >= 0)  best = fminf(best, gs[kl] + rr);
        if (kr < WW)  best = fminf(best, gs[kr] + rr);
    }
    float bg_w = expf(-best * INV2SIG2);

    // --- soft-target CE with log-softmax over C=6 ---
    float pv[CC];
#pragma unroll
    for (int c = 0; c < CC; ++c) pv[c] = pred[c * (HH * WW) + p];
    float m = pv[0];
#pragma unroll
    for (int c = 1; c < CC; ++c) m = fmaxf(m, pv[c]);
    float s = 0.0f;
#pragma unroll
    for (int c = 0; c < CC; ++c) s += expf(pv[c] - m);
    float lse = m + logf(s);
    const float* t = target + (size_t)p * CC;
    float ce = 0.0f;
#pragma unroll
    for (int c = 0; c < CC; ++c) ce += t[c] * (lse - pv[c]);

    // weights: channels 0..4 get 1.0, channel 5 gets bg_w; ce is shared
    // across channels -> contribution ce * (5 + bg_w)
    float contrib = ce * (5.0f + bg_w);

    // --- block reduction: wave64 shuffle then cross-wave via LDS ---
#pragma unroll
    for (int off = 32; off > 0; off >>= 1) contrib += __shfl_down(contrib, off, 64);
    if ((x & 63) == 0) red[x >> 6] = contrib;
    __syncthreads();
    if (x == 0) {
        float sum = 0.0f;
#pragma unroll
        for (int w = 0; w < 8; ++w) sum += red[w];
        partials[i] = sum;
    }
}

// ---------------- final reduce ----------------
__global__ void k_final(const float* __restrict__ partials, float* __restrict__ out) {
    __shared__ float red[8];
    const int x = threadIdx.x;  // 512 threads
    float v = partials[x];
#pragma unroll
    for (int off = 32; off > 0; off >>= 1) v += __shfl_down(v, off, 64);
    if ((x & 63) == 0) red[x >> 6] = v;
    __syncthreads();
    if (x == 0) {
        float sum = 0.0f;
#pragma unroll
        for (int w = 0; w < 8; ++w) sum += red[w];
        out[0] = sum / (float)(CC * HH * WW);
    }
}

extern "C" void kernel_launch(void* const* d_in, const int* in_sizes, int n_in,
                              void* d_out, int out_size, void* d_ws, size_t ws_size,
                              hipStream_t stream) {
    const float* pred   = (const float*)d_in[0];   // [1,6,512,512]
    const float* target = (const float*)d_in[1];   // [1,512,512,6]
    float* partials = (float*)d_ws;                // H floats
    float* out = (float*)d_out;

    k_main <<<HH, WW, 0, stream>>>(pred, target, partials);
    k_final<<<1, 512, 0, stream>>>(partials, out);
}